// Round 3
// baseline (97579.102 us; speedup 1.0000x reference)
//
#include <hip/hip_runtime.h>
#include <hip/hip_cooperative_groups.h>
#include <math.h>

namespace cg = cooperative_groups;

#define SEQ   512
#define BATCH 128
#define INP   512
#define HID   1024
#define G4    4096   // 4*HID
#define NOUT  4

// ---------------------------------------------------------------------------
// init: transpose h0,c0 [B][H] -> h_T,c_T [H][B]
// ---------------------------------------------------------------------------
__global__ void init_state(const float* __restrict__ h0, const float* __restrict__ c0,
                           float* __restrict__ hT, float* __restrict__ cT) {
  int idx = blockIdx.x * blockDim.x + threadIdx.x;  // < HID*BATCH
  int b = idx & (BATCH - 1);
  int j = idx >> 7;
  hT[j * BATCH + b] = h0[b * HID + j];
  cT[j * BATCH + b] = c0[b * HID + j];
}

// ---------------------------------------------------------------------------
// transpose a chunk of inputs: in [nrows][INP] -> xt [INP][nrows]
// ---------------------------------------------------------------------------
__global__ void transpose_in(const float* __restrict__ in, float* __restrict__ xt,
                             int nrows) {
  __shared__ float s[32][33];
  int tx = threadIdx.x & 31, ty = threadIdx.x >> 5;  // ty < 8
  int n0 = blockIdx.x * 32, i0 = blockIdx.y * 32;
#pragma unroll
  for (int r = 0; r < 4; r++) {
    int n = n0 + ty + 8 * r;
    s[ty + 8 * r][tx] = in[(size_t)n * INP + i0 + tx];
  }
  __syncthreads();
#pragma unroll
  for (int r = 0; r < 4; r++) {
    int i = i0 + ty + 8 * r;
    xt[(size_t)i * nrows + n0 + tx] = s[tx][ty + 8 * r];
  }
}

// ---------------------------------------------------------------------------
// gemm_xproj: C[4096][N] = W_ih[4096][512] @ Xt[512][N] + (b_ih + b_hh)
// tile 128x128, K-tile 32, thread = 8x8
// ---------------------------------------------------------------------------
__global__ __launch_bounds__(256, 3)
void gemm_xproj(const float* __restrict__ A, const float* __restrict__ Bm,
                const float* __restrict__ b_ih, const float* __restrict__ b_hh,
                float* __restrict__ C, int N) {
  __shared__ float As[32][128];
  __shared__ float Bs[32][128];
  int t = threadIdx.x;
  int g0 = blockIdx.x * 128;
  int n0 = blockIdx.y * 128;
  int mg = (t >> 4) * 8, nn = (t & 15) * 8;
  float acc[8][8] = {};
  for (int k0 = 0; k0 < INP; k0 += 32) {
#pragma unroll
    for (int r = 0; r < 4; r++) {
      int idx = t + 256 * r;            // 0..1023 : 128 rows x 8 float4
      int g = idx >> 3, i4 = idx & 7;
      float4 v = *(const float4*)&A[(size_t)(g0 + g) * INP + k0 + 4 * i4];
      As[4 * i4 + 0][g] = v.x; As[4 * i4 + 1][g] = v.y;
      As[4 * i4 + 2][g] = v.z; As[4 * i4 + 3][g] = v.w;
    }
#pragma unroll
    for (int r = 0; r < 4; r++) {
      int idx = t + 256 * r;            // 32 kk x 32 float4
      int kk = idx >> 5, n4 = idx & 31;
      *(float4*)&Bs[kk][4 * n4] = *(const float4*)&Bm[(size_t)(k0 + kk) * N + n0 + 4 * n4];
    }
    __syncthreads();
#pragma unroll 4
    for (int kk = 0; kk < 32; kk++) {
      float4 a0 = *(const float4*)&As[kk][mg];
      float4 a1 = *(const float4*)&As[kk][mg + 4];
      float4 bb0 = *(const float4*)&Bs[kk][nn];
      float4 bb1 = *(const float4*)&Bs[kk][nn + 4];
      float av[8] = {a0.x, a0.y, a0.z, a0.w, a1.x, a1.y, a1.z, a1.w};
      float bv[8] = {bb0.x, bb0.y, bb0.z, bb0.w, bb1.x, bb1.y, bb1.z, bb1.w};
#pragma unroll
      for (int i2 = 0; i2 < 8; i2++)
#pragma unroll
        for (int j2 = 0; j2 < 8; j2++)
          acc[i2][j2] = fmaf(av[i2], bv[j2], acc[i2][j2]);
    }
    __syncthreads();
  }
#pragma unroll
  for (int i2 = 0; i2 < 8; i2++) {
    int g = g0 + mg + i2;
    float bias = b_ih[g] + b_hh[g];
#pragma unroll
    for (int j2 = 0; j2 < 8; j2++) {
      C[(size_t)g * N + n0 + nn + j2] = acc[i2][j2] + bias;
    }
  }
}

// ---------------------------------------------------------------------------
// lstm_steps: PERSISTENT cooperative kernel. 256 blocks: mt = blk&31 (m-tile
// of 128 W-rows), kseg = blk>>5 (K-segment of 128). Phase 1: partial GEMM.
// __threadfence + grid.sync (device-scope visibility of `part` across XCDs).
// Phase 2: 512-element cell update. __threadfence + grid.sync (visibility of
// new hT before next step's staging reads).
// Row order inside m-tile: m = jj*4 + gate, global W row = gate*HID + j0+jj.
// ---------------------------------------------------------------------------
__global__ __launch_bounds__(256, 1)
void lstm_steps(const float* __restrict__ W, const float* __restrict__ xp,
                int N, int nsteps,
                float* hT, float* cT, float* part) {
  cg::grid_group grid = cg::this_grid();
  __shared__ float As[32][128];
  __shared__ float hs[32][128];
  int t = threadIdx.x;
  int blk = blockIdx.x;
  int mt = blk & 31;         // 0..31
  int kseg = blk >> 5;       // 0..7
  int j0 = mt * 32;
  int mg = (t >> 4) * 8, nn = (t & 15) * 8;
  float* dst = part + ((size_t)kseg * G4 + mt * 128) * BATCH;

  for (int tt = 0; tt < nsteps; tt++) {
    // ---- phase 1: partial GEMM over this block's K-segment ----
    float acc[8][8] = {};
    for (int kt = 0; kt < 4; kt++) {
      int k0 = kseg * 128 + kt * 32;
#pragma unroll
      for (int r = 0; r < 4; r++) {
        int idx = t + 256 * r;
        int m = idx >> 3, i4 = idx & 7;
        int row = (m & 3) * HID + j0 + (m >> 2);
        float4 v = *(const float4*)&W[(size_t)row * HID + k0 + 4 * i4];
        As[4 * i4 + 0][m] = v.x; As[4 * i4 + 1][m] = v.y;
        As[4 * i4 + 2][m] = v.z; As[4 * i4 + 3][m] = v.w;
      }
#pragma unroll
      for (int r = 0; r < 4; r++) {
        int idx = t + 256 * r;
        int kk = idx >> 5, b4 = idx & 31;
        *(float4*)&hs[kk][4 * b4] = *(const float4*)&hT[(size_t)(k0 + kk) * BATCH + 4 * b4];
      }
      __syncthreads();
#pragma unroll 4
      for (int kk = 0; kk < 32; kk++) {
        float4 a0 = *(const float4*)&As[kk][mg];
        float4 a1 = *(const float4*)&As[kk][mg + 4];
        float4 h0v = *(const float4*)&hs[kk][nn];
        float4 h1v = *(const float4*)&hs[kk][nn + 4];
        float av[8] = {a0.x, a0.y, a0.z, a0.w, a1.x, a1.y, a1.z, a1.w};
        float hv[8] = {h0v.x, h0v.y, h0v.z, h0v.w, h1v.x, h1v.y, h1v.z, h1v.w};
#pragma unroll
        for (int i2 = 0; i2 < 8; i2++)
#pragma unroll
          for (int j2 = 0; j2 < 8; j2++)
            acc[i2][j2] = fmaf(av[i2], hv[j2], acc[i2][j2]);
      }
      __syncthreads();
    }
#pragma unroll
    for (int i2 = 0; i2 < 8; i2++) {
      *(float4*)&dst[(size_t)(mg + i2) * BATCH + nn] =
          make_float4(acc[i2][0], acc[i2][1], acc[i2][2], acc[i2][3]);
      *(float4*)&dst[(size_t)(mg + i2) * BATCH + nn + 4] =
          make_float4(acc[i2][4], acc[i2][5], acc[i2][6], acc[i2][7]);
    }

    __threadfence();   // device-scope release: drain stores, writeback L2
    grid.sync();
    __threadfence();   // device-scope acquire: invalidate stale L1/L2 lines

    // ---- phase 2: cell update, 2 elements per thread ----
#pragma unroll
    for (int e = 0; e < 2; e++) {
      int idx = blk * 512 + t + 256 * e;   // < HID*BATCH
      int b = idx & (BATCH - 1);
      int j = idx >> 7;
      int rowbase = (j >> 5) * 128 + (j & 31) * 4;
      float pre[4];
#pragma unroll
      for (int g = 0; g < 4; g++) {
        float s = xp[(size_t)(g * HID + j) * N + (size_t)tt * BATCH + b];
#pragma unroll
        for (int p = 0; p < 8; p++)
          s += part[((size_t)p * G4 + rowbase + g) * BATCH + b];
        pre[g] = s;
      }
      float ig = 1.f / (1.f + expf(-pre[0]));
      float fg = 1.f / (1.f + expf(-pre[1]));
      float gg = tanhf(pre[2]);
      float og = 1.f / (1.f + expf(-pre[3]));
      float cn = fg * cT[idx] + ig * gg;
      cT[idx] = cn;
      hT[idx] = og * tanhf(cn);
    }

    __threadfence();   // release new hT/cT
    grid.sync();
    __threadfence();   // acquire before next step's hT staging
  }
}

// ---------------------------------------------------------------------------
// Fallback per-step kernels (round-1 proven path), used if cooperative
// launch is unavailable.
// ---------------------------------------------------------------------------
__global__ __launch_bounds__(256, 3)
void gemm_step(const float* __restrict__ W, const float* __restrict__ hT,
               float* __restrict__ part) {
  __shared__ float As[32][128];
  __shared__ float hs[32][128];
  int t = threadIdx.x;
  int mt = blockIdx.x;       // 0..31
  int kseg = blockIdx.y;     // 0..7
  int j0 = mt * 32;
  int mg = (t >> 4) * 8, nn = (t & 15) * 8;
  float acc[8][8] = {};
  for (int kt = 0; kt < 4; kt++) {
    int k0 = kseg * 128 + kt * 32;
#pragma unroll
    for (int r = 0; r < 4; r++) {
      int idx = t + 256 * r;
      int m = idx >> 3, i4 = idx & 7;
      int row = (m & 3) * HID + j0 + (m >> 2);
      float4 v = *(const float4*)&W[(size_t)row * HID + k0 + 4 * i4];
      As[4 * i4 + 0][m] = v.x; As[4 * i4 + 1][m] = v.y;
      As[4 * i4 + 2][m] = v.z; As[4 * i4 + 3][m] = v.w;
    }
#pragma unroll
    for (int r = 0; r < 4; r++) {
      int idx = t + 256 * r;
      int kk = idx >> 5, b4 = idx & 31;
      *(float4*)&hs[kk][4 * b4] = *(const float4*)&hT[(size_t)(k0 + kk) * BATCH + 4 * b4];
    }
    __syncthreads();
#pragma unroll 4
    for (int kk = 0; kk < 32; kk++) {
      float4 a0 = *(const float4*)&As[kk][mg];
      float4 a1 = *(const float4*)&As[kk][mg + 4];
      float4 h0v = *(const float4*)&hs[kk][nn];
      float4 h1v = *(const float4*)&hs[kk][nn + 4];
      float av[8] = {a0.x, a0.y, a0.z, a0.w, a1.x, a1.y, a1.z, a1.w};
      float hv[8] = {h0v.x, h0v.y, h0v.z, h0v.w, h1v.x, h1v.y, h1v.z, h1v.w};
#pragma unroll
      for (int i2 = 0; i2 < 8; i2++)
#pragma unroll
        for (int j2 = 0; j2 < 8; j2++)
          acc[i2][j2] = fmaf(av[i2], hv[j2], acc[i2][j2]);
    }
    __syncthreads();
  }
  float* dst = part + ((size_t)kseg * G4 + mt * 128) * BATCH;
#pragma unroll
  for (int i2 = 0; i2 < 8; i2++) {
    *(float4*)&dst[(size_t)(mg + i2) * BATCH + nn] =
        make_float4(acc[i2][0], acc[i2][1], acc[i2][2], acc[i2][3]);
    *(float4*)&dst[(size_t)(mg + i2) * BATCH + nn + 4] =
        make_float4(acc[i2][4], acc[i2][5], acc[i2][6], acc[i2][7]);
  }
}

__global__ void cell_update(const float* __restrict__ part, const float* __restrict__ xp,
                            int N, int tt, float* __restrict__ hT, float* __restrict__ cT) {
  int idx = blockIdx.x * blockDim.x + threadIdx.x;  // < HID*BATCH
  int b = idx & (BATCH - 1);
  int j = idx >> 7;
  int rowbase = (j >> 5) * 128 + (j & 31) * 4;
  float pre[4];
#pragma unroll
  for (int g = 0; g < 4; g++) {
    float s = xp[(size_t)(g * HID + j) * N + (size_t)tt * BATCH + b];
#pragma unroll
    for (int p = 0; p < 8; p++)
      s += part[((size_t)p * G4 + rowbase + g) * BATCH + b];
    pre[g] = s;
  }
  float ig = 1.f / (1.f + expf(-pre[0]));
  float fg = 1.f / (1.f + expf(-pre[1]));
  float gg = tanhf(pre[2]);
  float og = 1.f / (1.f + expf(-pre[3]));
  float cn = fg * cT[idx] + ig * gg;
  cT[idx] = cn;
  hT[idx] = og * tanhf(cn);
}

// ---------------------------------------------------------------------------
// decode + softmax over batch dim (axis 0)
// ---------------------------------------------------------------------------
__global__ void decode_softmax(const float* __restrict__ hT, const float* __restrict__ Wd,
                               const float* __restrict__ bd, float* __restrict__ out) {
  __shared__ float lg[NOUT][BATCH];
  __shared__ float mx[NOUT], sm[NOUT];
  int t = threadIdx.x;  // 512 threads
  int b = t >> 2, o = t & 3;
  float s = bd[o];
  for (int j = 0; j < HID; j++) s += hT[j * BATCH + b] * Wd[o * HID + j];
  lg[o][b] = s;
  __syncthreads();
  if (t < NOUT) {
    float m = -1e30f;
    for (int b2 = 0; b2 < BATCH; b2++) m = fmaxf(m, lg[t][b2]);
    float ss = 0.f;
    for (int b2 = 0; b2 < BATCH; b2++) ss += expf(lg[t][b2] - m);
    mx[t] = m; sm[t] = ss;
  }
  __syncthreads();
  out[b * NOUT + o] = expf(lg[o][b] - mx[o]) / sm[o];
}

// ---------------------------------------------------------------------------
extern "C" void kernel_launch(void* const* d_in, const int* in_sizes, int n_in,
                              void* d_out, int out_size, void* d_ws, size_t ws_size,
                              hipStream_t stream) {
  const float* inputs = (const float*)d_in[0];
  const float* h0     = (const float*)d_in[1];
  const float* c0     = (const float*)d_in[2];
  const float* W_ih   = (const float*)d_in[3];
  const float* W_hh   = (const float*)d_in[4];
  const float* b_ih   = (const float*)d_in[5];
  const float* b_hh   = (const float*)d_in[6];
  const float* W_dec  = (const float*)d_in[7];
  const float* b_dec  = (const float*)d_in[8];
  float* out = (float*)d_out;

  char* w = (char*)d_ws;
  float* hT = (float*)w;   w += (size_t)HID * BATCH * 4;
  float* cT = (float*)w;   w += (size_t)HID * BATCH * 4;
  float* part = (float*)w; w += (size_t)8 * G4 * BATCH * 4;
  size_t used = (size_t)(w - (char*)d_ws);

  // chunk size over timesteps, sized to fit ws (deterministic: ws_size const)
  size_t per_ct = ((size_t)INP * BATCH + (size_t)G4 * BATCH) * 4;  // Xt + XP per step
  int CT = 1;
  if (ws_size > used) {
    size_t avail = (ws_size - used) / per_ct;
    for (int c = SEQ; c >= 1; c >>= 1)
      if ((size_t)c <= avail) { CT = c; break; }
  }
  float* Xt = (float*)w;   w += (size_t)INP * BATCH * CT * 4;
  float* XP = (float*)w;
  int N = CT * BATCH;

  init_state<<<HID * BATCH / 256, 256, 0, stream>>>(h0, c0, hT, cT);

  for (int t0 = 0; t0 < SEQ; t0 += CT) {
    transpose_in<<<dim3(N / 32, INP / 32), 256, 0, stream>>>(
        inputs + (size_t)t0 * BATCH * INP, Xt, N);
    gemm_xproj<<<dim3(G4 / 128, N / 128), 256, 0, stream>>>(
        W_ih, Xt, b_ih, b_hh, XP, N);
    // persistent cooperative recurrence over this chunk
    const float* xp_c = XP;
    void* args[] = {(void*)&W_hh, (void*)&xp_c, (void*)&N, (void*)&CT,
                    (void*)&hT, (void*)&cT, (void*)&part};
    hipError_t ce = hipLaunchCooperativeKernel((void*)lstm_steps, dim3(256),
                                               dim3(256), args, 0, stream);
    if (ce != hipSuccess) {
      // deterministic fallback: proven round-1 per-step path
      for (int tt = 0; tt < CT; tt++) {
        gemm_step<<<dim3(32, 8), 256, 0, stream>>>(W_hh, hT, part);
        cell_update<<<HID * BATCH / 256, 256, 0, stream>>>(part, XP, N, tt, hT, cT);
      }
    }
  }

  decode_softmax<<<1, 512, 0, stream>>>(hT, W_dec, b_dec, out);
}

// Round 4
// 27783.737 us; speedup vs baseline: 3.5121x; 3.5121x over previous
//
#include <hip/hip_runtime.h>
#include <math.h>

#define SEQ   512
#define BATCH 128
#define INP   512
#define HID   1024
#define G4    4096   // 4*HID
#define NOUT  4

// ---------------------------------------------------------------------------
// init: transpose h0,c0 [B][H] -> hA,cT [H][B]
// ---------------------------------------------------------------------------
__global__ void init_state(const float* __restrict__ h0, const float* __restrict__ c0,
                           float* __restrict__ hT, float* __restrict__ cT) {
  int idx = blockIdx.x * blockDim.x + threadIdx.x;  // < HID*BATCH
  int b = idx & (BATCH - 1);
  int j = idx >> 7;
  hT[j * BATCH + b] = h0[b * HID + j];
  cT[j * BATCH + b] = c0[b * HID + j];
}

// ---------------------------------------------------------------------------
// transpose a chunk of inputs: in [nrows][INP] -> xt [INP][nrows]
// ---------------------------------------------------------------------------
__global__ void transpose_in(const float* __restrict__ in, float* __restrict__ xt,
                             int nrows) {
  __shared__ float s[32][33];
  int tx = threadIdx.x & 31, ty = threadIdx.x >> 5;  // ty < 8
  int n0 = blockIdx.x * 32, i0 = blockIdx.y * 32;
#pragma unroll
  for (int r = 0; r < 4; r++) {
    int n = n0 + ty + 8 * r;
    s[ty + 8 * r][tx] = in[(size_t)n * INP + i0 + tx];
  }
  __syncthreads();
#pragma unroll
  for (int r = 0; r < 4; r++) {
    int i = i0 + ty + 8 * r;
    xt[(size_t)i * nrows + n0 + tx] = s[tx][ty + 8 * r];
  }
}

// ---------------------------------------------------------------------------
// gemm_xproj: C[4096][N] = W_ih[4096][512] @ Xt[512][N] + (b_ih + b_hh)
// (unchanged, proven round-1 kernel)
// ---------------------------------------------------------------------------
__global__ __launch_bounds__(256, 3)
void gemm_xproj(const float* __restrict__ A, const float* __restrict__ Bm,
                const float* __restrict__ b_ih, const float* __restrict__ b_hh,
                float* __restrict__ C, int N) {
  __shared__ float As[32][128];
  __shared__ float Bs[32][128];
  int t = threadIdx.x;
  int g0 = blockIdx.x * 128;
  int n0 = blockIdx.y * 128;
  int mg = (t >> 4) * 8, nn = (t & 15) * 8;
  float acc[8][8] = {};
  for (int k0 = 0; k0 < INP; k0 += 32) {
#pragma unroll
    for (int r = 0; r < 4; r++) {
      int idx = t + 256 * r;
      int g = idx >> 3, i4 = idx & 7;
      float4 v = *(const float4*)&A[(size_t)(g0 + g) * INP + k0 + 4 * i4];
      As[4 * i4 + 0][g] = v.x; As[4 * i4 + 1][g] = v.y;
      As[4 * i4 + 2][g] = v.z; As[4 * i4 + 3][g] = v.w;
    }
#pragma unroll
    for (int r = 0; r < 4; r++) {
      int idx = t + 256 * r;
      int kk = idx >> 5, n4 = idx & 31;
      *(float4*)&Bs[kk][4 * n4] = *(const float4*)&Bm[(size_t)(k0 + kk) * N + n0 + 4 * n4];
    }
    __syncthreads();
#pragma unroll 4
    for (int kk = 0; kk < 32; kk++) {
      float4 a0 = *(const float4*)&As[kk][mg];
      float4 a1 = *(const float4*)&As[kk][mg + 4];
      float4 bb0 = *(const float4*)&Bs[kk][nn];
      float4 bb1 = *(const float4*)&Bs[kk][nn + 4];
      float av[8] = {a0.x, a0.y, a0.z, a0.w, a1.x, a1.y, a1.z, a1.w};
      float bv[8] = {bb0.x, bb0.y, bb0.z, bb0.w, bb1.x, bb1.y, bb1.z, bb1.w};
#pragma unroll
      for (int i2 = 0; i2 < 8; i2++)
#pragma unroll
        for (int j2 = 0; j2 < 8; j2++)
          acc[i2][j2] = fmaf(av[i2], bv[j2], acc[i2][j2]);
    }
    __syncthreads();
  }
#pragma unroll
  for (int i2 = 0; i2 < 8; i2++) {
    int g = g0 + mg + i2;
    float bias = b_ih[g] + b_hh[g];
#pragma unroll
    for (int j2 = 0; j2 < 8; j2++) {
      C[(size_t)g * N + n0 + nn + j2] = acc[i2][j2] + bias;
    }
  }
}

// ---------------------------------------------------------------------------
// lstm_step: ONE dispatch per timestep, fully fused GEMM + cell update.
// Grid 256 blocks: blk -> XCD-swizzled (mt 0..31: 32 j's, bs 0..7: 16 b's).
// Block owns full K=1024 for its (128 rows x 16 b) tile; K split across the
// 4 waves (256 each), reduced through LDS with one __syncthreads.
// Per thread (lane L, wave w): jj = L&31, bh = L>>5 -> 8 b's; 4 gate-rows of
// W read directly from global (L2-resident, no LDS staging -> no conflicts).
// acc[4][8] = 32 regs; 128 FMA per 12 loads per k-quad.
// Epilogue: cell update for block-local slice; cT private to block; hT
// ping-pong across dispatches (kernel-boundary coherence, proven in R1).
// ---------------------------------------------------------------------------
__global__ __launch_bounds__(256)
void lstm_step(const float* __restrict__ W, const float* __restrict__ xp, int N,
               const float* __restrict__ hin, float* __restrict__ hout,
               float* __restrict__ cT) {
  __shared__ float red[4][4][32][17];   // [wave][gate][jj][b(16)+pad]

  int blk = blockIdx.x;
  int x = blk & 7, b8 = blk >> 3;
  int mt = (x << 2) | (b8 >> 3);   // 0..31, XCD x serves mt 4x..4x+3 (W L2-local)
  int bs = b8 & 7;                 // 0..7 -> batch slice bs*16..+15
  int t = threadIdx.x;
  int w = t >> 6;                  // wave 0..3 -> K slice w*256..+255
  int lane = t & 63;
  int jj = lane & 31;              // j within tile
  int bh = lane >> 5;              // 0/1 -> 8-batch half
  int j = mt * 32 + jj;

  const float* wp0 = W + ((size_t)(0 * HID + j)) * HID + w * 256;
  const float* wp1 = W + ((size_t)(1 * HID + j)) * HID + w * 256;
  const float* wp2 = W + ((size_t)(2 * HID + j)) * HID + w * 256;
  const float* wp3 = W + ((size_t)(3 * HID + j)) * HID + w * 256;
  const float* hq  = hin + (size_t)(w * 256) * BATCH + bs * 16 + bh * 8;

  float acc[4][8] = {};
  for (int kq = 0; kq < 64; kq++) {          // 4 k per iter
    float4 w0 = *(const float4*)(wp0 + 4 * kq);
    float4 w1 = *(const float4*)(wp1 + 4 * kq);
    float4 w2 = *(const float4*)(wp2 + 4 * kq);
    float4 w3 = *(const float4*)(wp3 + 4 * kq);
    float wg[4][4] = {{w0.x, w0.y, w0.z, w0.w}, {w1.x, w1.y, w1.z, w1.w},
                      {w2.x, w2.y, w2.z, w2.w}, {w3.x, w3.y, w3.z, w3.w}};
#pragma unroll
    for (int e = 0; e < 4; e++) {
      const float* hp = hq + (size_t)(4 * kq + e) * BATCH;
      float4 h0 = *(const float4*)(hp);
      float4 h1 = *(const float4*)(hp + 4);
      float hb[8] = {h0.x, h0.y, h0.z, h0.w, h1.x, h1.y, h1.z, h1.w};
#pragma unroll
      for (int g = 0; g < 4; g++)
#pragma unroll
        for (int b = 0; b < 8; b++)
          acc[g][b] = fmaf(wg[g][e], hb[b], acc[g][b]);
    }
  }

  // dump per-wave partials to LDS (banks spread: jj*17 -> <=2-way, free)
#pragma unroll
  for (int g = 0; g < 4; g++)
#pragma unroll
    for (int b = 0; b < 8; b++)
      red[w][g][jj][bh * 8 + b] = acc[g][b];
  __syncthreads();

  // epilogue: thread -> (jj2 = t&31, sub = t>>5 -> 2 b's)
  int jj2 = t & 31;
  int sub = t >> 5;          // 0..7
  int j2 = mt * 32 + jj2;
  int bcol = bs * 16 + sub * 2;
  float hv[2], cv[2];
#pragma unroll
  for (int e2 = 0; e2 < 2; e2++) {
    int b = sub * 2 + e2;
    float pre[4];
#pragma unroll
    for (int g = 0; g < 4; g++) {
      float s = xp[(size_t)(g * HID + j2) * N + bcol + e2];
      s += red[0][g][jj2][b] + red[1][g][jj2][b] +
           red[2][g][jj2][b] + red[3][g][jj2][b];
      pre[g] = s;
    }
    float ig = 1.f / (1.f + expf(-pre[0]));
    float fg = 1.f / (1.f + expf(-pre[1]));
    float gg = tanhf(pre[2]);
    float og = 1.f / (1.f + expf(-pre[3]));
    float cold = cT[j2 * BATCH + bcol + e2];
    float cn = fg * cold + ig * gg;
    cv[e2] = cn;
    hv[e2] = og * tanhf(cn);
  }
  *(float2*)&cT[j2 * BATCH + bcol]   = make_float2(cv[0], cv[1]);
  *(float2*)&hout[j2 * BATCH + bcol] = make_float2(hv[0], hv[1]);
}

// ---------------------------------------------------------------------------
// decode + softmax over batch dim (axis 0)
// ---------------------------------------------------------------------------
__global__ void decode_softmax(const float* __restrict__ hT, const float* __restrict__ Wd,
                               const float* __restrict__ bd, float* __restrict__ out) {
  __shared__ float lg[NOUT][BATCH];
  __shared__ float mx[NOUT], sm[NOUT];
  int t = threadIdx.x;  // 512 threads
  int b = t >> 2, o = t & 3;
  float s = bd[o];
  for (int j = 0; j < HID; j++) s += hT[j * BATCH + b] * Wd[o * HID + j];
  lg[o][b] = s;
  __syncthreads();
  if (t < NOUT) {
    float m = -1e30f;
    for (int b2 = 0; b2 < BATCH; b2++) m = fmaxf(m, lg[t][b2]);
    float ss = 0.f;
    for (int b2 = 0; b2 < BATCH; b2++) ss += expf(lg[t][b2] - m);
    mx[t] = m; sm[t] = ss;
  }
  __syncthreads();
  out[b * NOUT + o] = expf(lg[o][b] - mx[o]) / sm[o];
}

// ---------------------------------------------------------------------------
extern "C" void kernel_launch(void* const* d_in, const int* in_sizes, int n_in,
                              void* d_out, int out_size, void* d_ws, size_t ws_size,
                              hipStream_t stream) {
  const float* inputs = (const float*)d_in[0];
  const float* h0     = (const float*)d_in[1];
  const float* c0     = (const float*)d_in[2];
  const float* W_ih   = (const float*)d_in[3];
  const float* W_hh   = (const float*)d_in[4];
  const float* b_ih   = (const float*)d_in[5];
  const float* b_hh   = (const float*)d_in[6];
  const float* W_dec  = (const float*)d_in[7];
  const float* b_dec  = (const float*)d_in[8];
  float* out = (float*)d_out;

  char* w = (char*)d_ws;
  float* hA = (float*)w;  w += (size_t)HID * BATCH * 4;
  float* hB = (float*)w;  w += (size_t)HID * BATCH * 4;
  float* cT = (float*)w;  w += (size_t)HID * BATCH * 4;
  size_t used = (size_t)(w - (char*)d_ws);

  // chunk size over timesteps, sized to fit ws (deterministic: ws_size const)
  size_t per_ct = ((size_t)INP * BATCH + (size_t)G4 * BATCH) * 4;  // Xt + XP per step
  int CT = 1;
  if (ws_size > used) {
    size_t avail = (ws_size - used) / per_ct;
    for (int c = SEQ; c >= 1; c >>= 1)
      if ((size_t)c <= avail) { CT = c; break; }
  }
  float* Xt = (float*)w;  w += (size_t)INP * BATCH * CT * 4;
  float* XP = (float*)w;
  int N = CT * BATCH;

  float* hbuf[2] = {hA, hB};

  init_state<<<HID * BATCH / 256, 256, 0, stream>>>(h0, c0, hA, cT);

  for (int t0 = 0; t0 < SEQ; t0 += CT) {
    transpose_in<<<dim3(N / 32, INP / 32), 256, 0, stream>>>(
        inputs + (size_t)t0 * BATCH * INP, Xt, N);
    gemm_xproj<<<dim3(G4 / 128, N / 128), 256, 0, stream>>>(
        W_ih, Xt, b_ih, b_hh, XP, N);
    for (int tt = 0; tt < CT; tt++) {
      int gs = t0 + tt;                       // global step index
      const float* xpc = XP + (size_t)tt * BATCH;  // column block for this step
      lstm_step<<<256, 256, 0, stream>>>(
          W_hh, xpc, N, hbuf[gs & 1], hbuf[1 - (gs & 1)], cT);
    }
  }

  // SEQ even -> final h is in hbuf[0]
  decode_softmax<<<1, 512, 0, stream>>>(hA, W_dec, b_dec, out);
}